// Round 9
// baseline (186.058 us; speedup 1.0000x reference)
//
#include <hip/hip_runtime.h>
#include <hip/hip_bf16.h>
#include <math.h>

typedef __bf16 bf16_t;
typedef __bf16 bf16x8 __attribute__((ext_vector_type(8)));
typedef __bf16 bf16x4 __attribute__((ext_vector_type(4)));
typedef __bf16 bf16x2 __attribute__((ext_vector_type(2)));
typedef float f32x4 __attribute__((ext_vector_type(4)));
typedef unsigned u32x4 __attribute__((ext_vector_type(4)));

// scale 1/sqrt(1024) folded with log2(e), plus half-ulp rounding bias
// (x * 2^0.0028169 = x * (1+2^-9)) so perm-truncation rounds on average.
#define SCALE_L2E 0.045084234f
#define ROUND_B 0.0028169f

#define MFMA16(a, b, c) __builtin_amdgcn_mfma_f32_16x16x32_bf16(a, b, c, 0, 0, 0)

// pack two f32 into bf16x2 (truncate): dst = (hi16(b) << 16) | hi16(a)
__device__ __forceinline__ unsigned pack2(float a, float b) {
  return __builtin_amdgcn_perm(__builtin_bit_cast(unsigned, b),
                               __builtin_bit_cast(unsigned, a), 0x07060302u);
}

// ---------------------------------------------------------------------------
// fused f32 -> bf16 convert of three buffers (x, w_qkv, w_o), 8 elems/thread
// ---------------------------------------------------------------------------
__global__ void convert3_f32_bf16(const float* __restrict__ a, int na,
                                  const float* __restrict__ b, int nb,
                                  const float* __restrict__ c, int nc,
                                  bf16_t* __restrict__ oa, bf16_t* __restrict__ ob,
                                  bf16_t* __restrict__ oc) {
  int i = (blockIdx.x * blockDim.x + threadIdx.x) * 8;
  const float* src;
  bf16_t* dst;
  int off;
  if (i < na) { src = a; dst = oa; off = i; }
  else if (i < na + nb) { src = b; dst = ob; off = i - na; }
  else if (i < na + nb + nc) { src = c; dst = oc; off = i - na - nb; }
  else return;
  float4 u = *(const float4*)&src[off];
  float4 v = *(const float4*)&src[off + 4];
  bf16x8 w = {(bf16_t)u.x, (bf16_t)u.y, (bf16_t)u.z, (bf16_t)u.w,
              (bf16_t)v.x, (bf16_t)v.y, (bf16_t)v.z, (bf16_t)v.w};
  *(bf16x8*)&dst[off] = w;
}

// ---------------------------------------------------------------------------
// m97-style BT-GEMM, bf16 in: C[m,n] = sum_k A[m,k]*B[n,k] + bias[n]
// (unchanged — passed R5..R8)
// ---------------------------------------------------------------------------
#define GLOBAL_AS __attribute__((address_space(1)))
#define LDS_AS __attribute__((address_space(3)))
__device__ __forceinline__ void g2l16(const void* g, void* l) {
  __builtin_amdgcn_global_load_lds((const GLOBAL_AS void*)g, (LDS_AS void*)l,
                                   16, 0, 0);
}

template <typename TC, int BN>
__launch_bounds__(256)
__global__ void gemm_bt_bias(const bf16_t* __restrict__ A,
                             const bf16_t* __restrict__ B,
                             const float* __restrict__ bias,
                             TC* __restrict__ C,
                             int M, int N, int K) {
  constexpr int NT = BN / 32;  // n-frags per wave
  __shared__ bf16_t As[128 * 32];
  __shared__ bf16_t Bs[BN * 32];

  const int t = threadIdx.x;
  const int wave = t >> 6, lane = t & 63, quad = lane >> 4, ln = lane & 15;
  const int wm = (wave >> 1) * 64, wn = (wave & 1) * (BN / 2);
  const int m0 = blockIdx.y * 128, n0 = blockIdx.x * BN;

  const int srow = lane >> 2;
  const int schunk = ((lane & 3) ^ ((lane >> 3) & 3)) * 8;
  const bf16_t* gA0 = &A[(size_t)(m0 + wave * 32 + srow) * K + schunk];
  const bf16_t* gA1 = gA0 + (size_t)16 * K;
  bf16_t* lA0 = &As[(wave * 32) * 32];
  bf16_t* lA1 = &As[(wave * 32 + 16) * 32];
  const bf16_t* gB0 = &B[(size_t)(n0 + (BN == 128 ? wave * 32 : wave * 16) + srow) * K + schunk];
  const bf16_t* gB1 = gB0 + (size_t)16 * K;
  bf16_t* lB0 = &Bs[((BN == 128 ? wave * 32 : wave * 16)) * 32];
  bf16_t* lB1 = &Bs[(wave * 32 + 16) * 32];

  const int cslot = (quad ^ ((ln >> 1) & 3)) * 8;

  f32x4 acc[4][NT];
  for (int i = 0; i < 4; i++)
    for (int j = 0; j < NT; j++) acc[i][j] = (f32x4){0.f, 0.f, 0.f, 0.f};

  for (int k0 = 0; k0 < K; k0 += 32) {
    __syncthreads();
    g2l16(gA0 + k0, lA0);
    g2l16(gA1 + k0, lA1);
    g2l16(gB0 + k0, lB0);
    if (BN == 128) g2l16(gB1 + k0, lB1);
    __syncthreads();

    bf16x8 af[4], bfr[NT];
    for (int mt = 0; mt < 4; mt++)
      af[mt] = *(const bf16x8*)&As[(wm + mt * 16 + ln) * 32 + cslot];
    for (int nt = 0; nt < NT; nt++)
      bfr[nt] = *(const bf16x8*)&Bs[(wn + nt * 16 + ln) * 32 + cslot];
    for (int mt = 0; mt < 4; mt++)
      for (int nt = 0; nt < NT; nt++)
        acc[mt][nt] = MFMA16(af[mt], bfr[nt], acc[mt][nt]);
  }

  for (int nt = 0; nt < NT; nt++) {
    int col = n0 + wn + nt * 16 + ln;
    float bv = bias[col];
    for (int mt = 0; mt < 4; mt++) {
      int row = m0 + wm + mt * 16 + quad * 4;
      for (int r = 0; r < 4; r++)
        C[(size_t)(row + r) * N + col] = (TC)(acc[mt][nt][r] + bv);
    }
  }
}

// ---------------------------------------------------------------------------
// Causal attention, SINGLE q-tile per block for occupancy: 1024 blocks
// (32 bh x 32 q-tiles) -> 4 blocks/CU co-resident (dbuf LDS 36.9KB x4 =
// 147.5KB, VGPR < 128 at launch_bounds(256,4)). Work balance via perm
// mapping: i = (blk&7)*4 + (blk>>8); j = i&1 ? 31-(i>>1) : i>>1 — any
// stride-256 residency set sums to exactly 66 units, bijective per bh.
// MFMA layout chaining (S^T -> P^T B-frags, fused-pair K=32 PV), peeled
// diagonal masking, l via MFMA-ones (layout-invariant A; masked zeros in Bp
// keep it exact; all C rows equal so l = lacc[0], no cross-lane reduce).
// ---------------------------------------------------------------------------
__launch_bounds__(256, 4)
__global__ void attn_kernel(const bf16_t* __restrict__ qkv,
                            bf16_t* __restrict__ out) {
  constexpr int KP = 72, VP = 72;
  constexpr int BUF = 64 * KP;  // elems per K (or V) buffer
  __shared__ __align__(16) bf16_t KsB[2 * BUF];  // [buf][k][d], swizzled
  __shared__ __align__(16) bf16_t VtB[2 * BUF];  // [buf][d][k], swizzled

  const int t = threadIdx.x;
  const int wave = t >> 6, lane = t & 63, quad = lane >> 4, ln = lane & 15;
  const int g = blockIdx.x & 255, s = blockIdx.x >> 8;  // s in 0..3
  const int bh = g >> 3;
  const int i = (g & 7) * 4 + s;                         // 0..31
  const int j = (i & 1) ? (31 - (i >> 1)) : (i >> 1);    // q-tile index
  const int b = bh >> 4, h = bh & 15;
  const int qT = j * 64;
  const int ntiles = j + 1;
  const size_t rs = 3072;
  const size_t base = (size_t)b * 2048 * rs;

  // Q as B-operand frags: B[d=quad*8+jj][q=ln] = Q[q][d]
  const size_t qoff = base + (size_t)(qT + wave * 16 + ln) * rs + h * 64;
  bf16x8 qf0 = *(const bf16x8*)&qkv[qoff + quad * 8];
  bf16x8 qf1 = *(const bf16x8*)&qkv[qoff + 32 + quad * 8];

  // O^T accumulators: rows d = ct*16+quad*4+r, col q = ln; l via MFMA-ones
  f32x4 o[4];
  f32x4 lacc = (f32x4){0.f, 0.f, 0.f, 0.f};
  for (int ct = 0; ct < 4; ct++) o[ct] = (f32x4){0.f, 0.f, 0.f, 0.f};
  bf16x8 ones;
#pragma unroll
  for (int z = 0; z < 8; z++) ones[z] = (bf16_t)1.0f;

  // staging maps: K rows r0, r0+32 (b128); V rows 2*r0, 2*r0+1 (b32 pairs)
  const int r0 = t >> 3, c0 = (t & 7) * 8;
  const int ksA = r0 * KP + (((t & 7) + wave) & 7) * 8;  // r0>>3 == wave
  const int ksB2 = (r0 + 32) * KP + (((t & 7) + wave + 4) & 7) * 8;
  const int vkoff = ((((r0 >> 2) + (t & 7)) & 7)) * 8 + 2 * (r0 & 3);

  // running global prefetch pointers (advance by 64 rows per tile)
  const bf16_t* kpa = &qkv[base + 1024 + h * 64 + (size_t)r0 * rs + c0];
  const bf16_t* kpb = kpa + (size_t)32 * rs;
  const bf16_t* vpa = &qkv[base + 2048 + h * 64 + (size_t)(2 * r0) * rs + c0];
  const bf16_t* vpb = vpa + rs;
  const size_t tstep = (size_t)64 * rs;

  // tile 0 into regs
  bf16x8 ka = *(const bf16x8*)kpa; kpa += tstep;
  bf16x8 kb = *(const bf16x8*)kpb; kpb += tstep;
  bf16x8 va2 = *(const bf16x8*)vpa; vpa += tstep;
  bf16x8 vb2 = *(const bf16x8*)vpb; vpb += tstep;

  const int qg = qT + wave * 16 + ln;  // lane's q (S^T column)

  auto stage_to = [&](int buf) {
    bf16_t* KsW = &KsB[buf * BUF];
    bf16_t* VtW = &VtB[buf * BUF];
    *(bf16x8*)&KsW[ksA] = ka;
    *(bf16x8*)&KsW[ksB2] = kb;
#pragma unroll
    for (int z = 0; z < 8; z++) {
      bf16x2 w2 = {va2[z], vb2[z]};
      *(bf16x2*)&VtW[(c0 + z) * VP + vkoff] = w2;
    }
  };
  auto prefetch = [&]() {
    ka = *(const bf16x8*)kpa; kpa += tstep;
    kb = *(const bf16x8*)kpb; kpb += tstep;
    va2 = *(const bf16x8*)vpa; vpa += tstep;
    vb2 = *(const bf16x8*)vpb; vpb += tstep;
  };

  // body for one k-tile; `masked` literal at call sites
  auto body = [&](int kt, bool masked) {
    if (kt + 1 < ntiles) {
      stage_to((kt + 1) & 1);
      if (kt + 2 < ntiles) prefetch();
    }
    const bf16_t* Ks = &KsB[(kt & 1) * BUF];
    const bf16_t* Vt = &VtB[(kt & 1) * BUF];

    // QK^T transposed + exp + perm-pack into fused K=32 B-frags
    bf16x8 Bp[2];
#pragma unroll
    for (int pr = 0; pr < 2; pr++) {
      u32x4 u;
#pragma unroll
      for (int sh = 0; sh < 2; sh++) {
        const int st = pr * 2 + sh;
        const int krow = st * 16 + ln;
        const int rot = 2 * st + (ln >> 3);
        bf16x8 kf0 = *(const bf16x8*)&Ks[krow * KP + ((quad + rot) & 7) * 8];
        bf16x8 kf1 = *(const bf16x8*)&Ks[krow * KP + ((quad + 4 + rot) & 7) * 8];
        f32x4 sc = (f32x4){0.f, 0.f, 0.f, 0.f};
        sc = MFMA16(kf0, qf0, sc);
        sc = MFMA16(kf1, qf1, sc);
        const int k0g = kt * 64 + st * 16 + quad * 4;
        float pv[4];
#pragma unroll
        for (int r = 0; r < 4; r++) {
          float e = __builtin_amdgcn_exp2f(fmaf(sc[r], SCALE_L2E, ROUND_B));
          if (masked && (k0g + r > qg)) e = 0.f;
          pv[r] = e;
        }
        u[sh * 2] = pack2(pv[0], pv[1]);
        u[sh * 2 + 1] = pack2(pv[2], pv[3]);
      }
      Bp[pr] = __builtin_bit_cast(bf16x8, u);
    }

    // PV + l: O^T += A8(V^T) x Bp; lacc += ones x Bp
#pragma unroll
    for (int pr = 0; pr < 2; pr++) {
      lacc = MFMA16(ones, Bp[pr], lacc);
#pragma unroll
      for (int ct = 0; ct < 4; ct++) {
        const int dd = ct * 16 + ln;
        const int bc = (quad >> 1) + 2 * ct + (ln >> 3);
        const int cA = (4 * pr + bc) & 7;
        const int cB = (4 * pr + 2 + bc) & 7;
        bf16x4 v0 = *(const bf16x4*)&Vt[dd * VP + cA * 8 + (quad & 1) * 4];
        bf16x4 v1 = *(const bf16x4*)&Vt[dd * VP + cB * 8 + (quad & 1) * 4];
        bf16x8 A8 = __builtin_shufflevector(v0, v1, 0, 1, 2, 3, 4, 5, 6, 7);
        o[ct] = MFMA16(A8, Bp[pr], o[ct]);
      }
    }
    if (kt + 1 < ntiles) __syncthreads();
  };

  // prologue: tile 0 into buf0, prefetch tile 1, sync
  stage_to(0);
  if (ntiles > 1) prefetch();
  __syncthreads();

  for (int kt = 0; kt < ntiles - 1; kt++) body(kt, false);
  body(ntiles - 1, true);  // diagonal tile

  // normalize + store; all lacc rows equal -> l = lacc[0], no reduction
  const float inv = __builtin_amdgcn_rcpf(lacc[0]);
  const int ocol = h * 64 + quad * 4;
#pragma unroll
  for (int ct = 0; ct < 4; ct++) {
    bf16x4 w;
#pragma unroll
    for (int r = 0; r < 4; r++) w[r] = (bf16_t)(o[ct][r] * inv);
    *(bf16x4*)&out[(size_t)(b * 2048 + qg) * 1024 + ocol + ct * 16] = w;
  }
}

extern "C" void kernel_launch(void* const* d_in, const int* in_sizes, int n_in,
                              void* d_out, int out_size, void* d_ws, size_t ws_size,
                              hipStream_t stream) {
  const float* x     = (const float*)d_in[0];  // [2,2048,1024]
  const float* w_qkv = (const float*)d_in[1];  // [3072,1024]
  const float* b_qkv = (const float*)d_in[2];  // [3072]
  const float* w_o   = (const float*)d_in[3];  // [1024,1024]
  const float* b_o   = (const float*)d_in[4];  // [1024]
  float* out = (float*)d_out;                  // [2,2048,1024]

  // workspace (bf16): qkv | xbf/attn (aliased) | wqkv_bf | wo_bf  = 42 MB
  bf16_t* qkv   = (bf16_t*)d_ws;
  bf16_t* xbf   = qkv + (size_t)4096 * 3072;
  bf16_t* wqkvb = xbf + (size_t)4096 * 1024;
  bf16_t* wob   = wqkvb + (size_t)3072 * 1024;
  bf16_t* attn  = xbf;  // x dead after GEMM1

  const int na = 4096 * 1024, nb = 3072 * 1024, nc = 1024 * 1024;
  convert3_f32_bf16<<<dim3((na + nb + nc) / (256 * 8)), 256, 0, stream>>>(
      x, na, w_qkv, nb, w_o, nc, xbf, wqkvb, wob);

  // 1) qkv = x @ w_qkv^T + b_qkv   (768 blocks, 3/CU)
  gemm_bt_bias<bf16_t, 128><<<dim3(3072 / 128, 4096 / 128), 256, 0, stream>>>(
      xbf, wqkvb, b_qkv, qkv, 4096, 3072, 1024);
  // 2) causal attention: 1024 blocks = 32 bh x 32 q-tiles (perm-balanced)
  attn_kernel<<<dim3(1024), 256, 0, stream>>>(qkv, attn);
  // 3) out = attn @ w_o^T + b_o    (128x64 tiles -> 512 blocks, 2/CU)
  gemm_bt_bias<float, 64><<<dim3(1024 / 64, 4096 / 128), 256, 0, stream>>>(
      attn, wob, b_o, out, 4096, 1024, 1024);
}

// Round 10
// 180.461 us; speedup vs baseline: 1.0310x; 1.0310x over previous
//
#include <hip/hip_runtime.h>
#include <hip/hip_bf16.h>
#include <math.h>

typedef __bf16 bf16_t;
typedef __bf16 bf16x8 __attribute__((ext_vector_type(8)));
typedef __bf16 bf16x4 __attribute__((ext_vector_type(4)));
typedef __bf16 bf16x2 __attribute__((ext_vector_type(2)));
typedef float f32x4 __attribute__((ext_vector_type(4)));
typedef unsigned u32x4 __attribute__((ext_vector_type(4)));

// scale 1/sqrt(1024) folded with log2(e), plus half-ulp rounding bias
// (x * 2^0.0028169 = x * (1+2^-9)) so perm-truncation rounds on average.
#define SCALE_L2E 0.045084234f
#define ROUND_B 0.0028169f

#define MFMA16(a, b, c) __builtin_amdgcn_mfma_f32_16x16x32_bf16(a, b, c, 0, 0, 0)

// pack two f32 into bf16x2 (truncate): dst = (hi16(b) << 16) | hi16(a)
__device__ __forceinline__ unsigned pack2(float a, float b) {
  return __builtin_amdgcn_perm(__builtin_bit_cast(unsigned, b),
                               __builtin_bit_cast(unsigned, a), 0x07060302u);
}

// ---------------------------------------------------------------------------
// fused f32 -> bf16 convert of three buffers (x, w_qkv, w_o), 8 elems/thread
// ---------------------------------------------------------------------------
__global__ void convert3_f32_bf16(const float* __restrict__ a, int na,
                                  const float* __restrict__ b, int nb,
                                  const float* __restrict__ c, int nc,
                                  bf16_t* __restrict__ oa, bf16_t* __restrict__ ob,
                                  bf16_t* __restrict__ oc) {
  int i = (blockIdx.x * blockDim.x + threadIdx.x) * 8;
  const float* src;
  bf16_t* dst;
  int off;
  if (i < na) { src = a; dst = oa; off = i; }
  else if (i < na + nb) { src = b; dst = ob; off = i - na; }
  else if (i < na + nb + nc) { src = c; dst = oc; off = i - na - nb; }
  else return;
  float4 u = *(const float4*)&src[off];
  float4 v = *(const float4*)&src[off + 4];
  bf16x8 w = {(bf16_t)u.x, (bf16_t)u.y, (bf16_t)u.z, (bf16_t)u.w,
              (bf16_t)v.x, (bf16_t)v.y, (bf16_t)v.z, (bf16_t)v.w};
  *(bf16x8*)&dst[off] = w;
}

// ---------------------------------------------------------------------------
// BT-GEMM, BK=64: C[m,n] = sum_k A[m,k]*B[n,k] + bias[n]. 128 x BN tile,
// 256 thr = 4 waves (2x2 of 64x(BN/2)). 16 K-iters (vs 32 at BK=32) halves
// barrier-drain count. Staging: g2l16 width=16, 8-row calls (1KB each);
// lane fetches swizzled global chunk (lane&7)^(lane>>3) so the DMA'd LDS
// layout has phys = logical ^ (row&7); frag slot (h*4+quad)^(ln&7) matches
// (row bases all == 0 mod 8). LDS: As 16KB + Bs 8/16KB.
// ---------------------------------------------------------------------------
#define GLOBAL_AS __attribute__((address_space(1)))
#define LDS_AS __attribute__((address_space(3)))
__device__ __forceinline__ void g2l16(const void* g, void* l) {
  __builtin_amdgcn_global_load_lds((const GLOBAL_AS void*)g, (LDS_AS void*)l,
                                   16, 0, 0);
}

template <typename TC, int BN>
__launch_bounds__(256)
__global__ void gemm_bt_bias(const bf16_t* __restrict__ A,
                             const bf16_t* __restrict__ B,
                             const float* __restrict__ bias,
                             TC* __restrict__ C,
                             int M, int N, int K) {
  constexpr int NT = BN / 32;      // n-frags per wave (4 or 2)
  constexpr int BCALLS = BN / 32;  // B staging calls per thread (4 or 2)
  __shared__ bf16_t As[128 * 64];
  __shared__ bf16_t Bs[BN * 64];

  const int t = threadIdx.x;
  const int wave = t >> 6, lane = t & 63, quad = lane >> 4, ln = lane & 15;
  const int wm = (wave >> 1) * 64, wn = (wave & 1) * (BN / 2);
  const int m0 = blockIdx.y * 128, n0 = blockIdx.x * BN;

  const int rown = lane >> 3;                  // row within an 8-row call
  const int chunk = ((lane & 7) ^ rown) * 8;   // swizzled global elem offset
  const bf16_t* gA = &A[(size_t)(m0 + wave * 32 + rown) * K + chunk];
  const bf16_t* gB =
      &B[(size_t)(n0 + (BN == 128 ? wave * 32 : wave * 16) + rown) * K + chunk];
  bf16_t* lA = &As[(wave * 32) * 64];
  bf16_t* lB = &Bs[(BN == 128 ? wave * 32 : wave * 16) * 64];

  // frag read slots for k-half 0 / 1 (elems; constant per thread)
  const int cs0 = ((0 + quad) ^ (ln & 7)) * 8;
  const int cs1 = ((4 + quad) ^ (ln & 7)) * 8;

  f32x4 acc[4][NT];
  for (int i = 0; i < 4; i++)
    for (int j = 0; j < NT; j++) acc[i][j] = (f32x4){0.f, 0.f, 0.f, 0.f};

  for (int k0 = 0; k0 < K; k0 += 64) {
    __syncthreads();
#pragma unroll
    for (int c = 0; c < 4; c++)
      g2l16(gA + k0 + (size_t)(c * 8) * K, lA + c * 8 * 64);
#pragma unroll
    for (int c = 0; c < BCALLS; c++)
      g2l16(gB + k0 + (size_t)(c * 8) * K, lB + c * 8 * 64);
    __syncthreads();

#pragma unroll
    for (int h = 0; h < 2; h++) {
      const int cs = h ? cs1 : cs0;
      bf16x8 af[4], bfr[NT];
#pragma unroll
      for (int mt = 0; mt < 4; mt++)
        af[mt] = *(const bf16x8*)&As[(wm + mt * 16 + ln) * 64 + cs];
#pragma unroll
      for (int nt = 0; nt < NT; nt++)
        bfr[nt] = *(const bf16x8*)&Bs[(wn + nt * 16 + ln) * 64 + cs];
#pragma unroll
      for (int mt = 0; mt < 4; mt++)
#pragma unroll
        for (int nt = 0; nt < NT; nt++)
          acc[mt][nt] = MFMA16(af[mt], bfr[nt], acc[mt][nt]);
    }
  }

  for (int nt = 0; nt < NT; nt++) {
    int col = n0 + wn + nt * 16 + ln;
    float bv = bias[col];
    for (int mt = 0; mt < 4; mt++) {
      int row = m0 + wm + mt * 16 + quad * 4;
      for (int r = 0; r < 4; r++)
        C[(size_t)(row + r) * N + col] = (TC)(acc[mt][nt][r] + bv);
    }
  }
}

// ---------------------------------------------------------------------------
// Causal attention (R7 kernel, verbatim — measured 44 µs): MFMA layout
// chaining, fused-pair K=32 PV, double-buffered LDS (1 barrier/iter), peeled
// causal phases. Block = paired q-tiles (p, 31-p): 512 blocks, equal work,
// 2/CU co-resident; in-wave kf/vf reuse across the two q-sets is the key
// data-reuse (R8's single-tile 4/CU variant lost it and regressed).
// GRID MUST BE 512 (1024 clobbers wob via phantom b=2,3 — R4 failure).
// ---------------------------------------------------------------------------
__launch_bounds__(256, 2)
__global__ void attn_kernel(const bf16_t* __restrict__ qkv,
                            bf16_t* __restrict__ out) {
  constexpr int KP = 72, VP = 72;
  constexpr int BUF = 64 * KP;  // elems per K (or V) buffer
  __shared__ __align__(16) bf16_t KsB[2 * BUF];  // [buf][k][d], swizzled
  __shared__ __align__(16) bf16_t VtB[2 * BUF];  // [buf][d][k], swizzled

  const int t = threadIdx.x;
  const int wave = t >> 6, lane = t & 63, quad = lane >> 4, ln = lane & 15;
  const int p = blockIdx.x & 15;   // pair: q-tiles p and 31-p
  const int bh = blockIdx.x >> 4;  // 0..31
  const int b = bh >> 4, h = bh & 15;
  const int qA = p * 64, qB = (31 - p) * 64;
  const int ntiles = 32 - p;       // A active for kt <= p; B for all
  const size_t rs = 3072;
  const size_t base = (size_t)b * 2048 * rs;

  // Q as B-operand frags: B[d=quad*8+j][q=ln] = Q[q][d]
  const size_t qoffA = base + (size_t)(qA + wave * 16 + ln) * rs + h * 64;
  const size_t qoffB = base + (size_t)(qB + wave * 16 + ln) * rs + h * 64;
  bf16x8 qfA0 = *(const bf16x8*)&qkv[qoffA + quad * 8];
  bf16x8 qfA1 = *(const bf16x8*)&qkv[qoffA + 32 + quad * 8];
  bf16x8 qfB0 = *(const bf16x8*)&qkv[qoffB + quad * 8];
  bf16x8 qfB1 = *(const bf16x8*)&qkv[qoffB + 32 + quad * 8];

  // O^T accumulators: rows d = ct*16+quad*4+r, col q = ln
  f32x4 oA[4], oB[4];
  float lAx = 0.f, lBx = 0.f;
  for (int ct = 0; ct < 4; ct++) {
    oA[ct] = (f32x4){0.f, 0.f, 0.f, 0.f};
    oB[ct] = (f32x4){0.f, 0.f, 0.f, 0.f};
  }

  // staging maps: K rows r0, r0+32 (b128); V rows 2*r0, 2*r0+1 (b32 pairs)
  const int r0 = t >> 3, c0 = (t & 7) * 8;
  const int ksA = r0 * KP + (((t & 7) + wave) & 7) * 8;  // r0>>3 == wave
  const int ksB2 = (r0 + 32) * KP + (((t & 7) + wave + 4) & 7) * 8;
  const int vkoff = ((((r0 >> 2) + (t & 7)) & 7)) * 8 + 2 * (r0 & 3);

  // running global prefetch pointers (advance by 64 rows per tile)
  const bf16_t* kpa = &qkv[base + 1024 + h * 64 + (size_t)r0 * rs + c0];
  const bf16_t* kpb = kpa + (size_t)32 * rs;
  const bf16_t* vpa = &qkv[base + 2048 + h * 64 + (size_t)(2 * r0) * rs + c0];
  const bf16_t* vpb = vpa + rs;
  const size_t tstep = (size_t)64 * rs;

  // tile 0 into regs
  bf16x8 ka = *(const bf16x8*)kpa; kpa += tstep;
  bf16x8 kb = *(const bf16x8*)kpb; kpb += tstep;
  bf16x8 va2 = *(const bf16x8*)vpa; vpa += tstep;
  bf16x8 vb2 = *(const bf16x8*)vpb; vpb += tstep;

  const int qgA = qA + wave * 16 + ln;  // lane's q (S^T column), set A
  const int qgB = qB + wave * 16 + ln;

  auto stage_to = [&](int buf) {
    bf16_t* KsW = &KsB[buf * BUF];
    bf16_t* VtW = &VtB[buf * BUF];
    *(bf16x8*)&KsW[ksA] = ka;
    *(bf16x8*)&KsW[ksB2] = kb;
#pragma unroll
    for (int j = 0; j < 8; j++) {
      bf16x2 w2 = {va2[j], vb2[j]};
      *(bf16x2*)&VtW[(c0 + j) * VP + vkoff] = w2;
    }
  };
  auto prefetch = [&]() {
    ka = *(const bf16x8*)kpa; kpa += tstep;
    kb = *(const bf16x8*)kpb; kpb += tstep;
    va2 = *(const bf16x8*)vpa; vpa += tstep;
    vb2 = *(const bf16x8*)vpb; vpb += tstep;
  };
  auto load_kfs = [&](const bf16_t* Ks, bf16x8* kf0s, bf16x8* kf1s) {
#pragma unroll
    for (int st = 0; st < 4; st++) {
      const int krow = st * 16 + ln;
      const int rot = 2 * st + (ln >> 3);
      kf0s[st] = *(const bf16x8*)&Ks[krow * KP + ((quad + rot) & 7) * 8];
      kf1s[st] = *(const bf16x8*)&Ks[krow * KP + ((quad + 4 + rot) & 7) * 8];
    }
  };
  auto qk_block = [&](const bf16x8* kf0s, const bf16x8* kf1s, bf16x8 q0,
                      bf16x8 q1, float& lx, bf16x8* Bp, bool masked,
                      int kbase, int qg) {
#pragma unroll
    for (int pr = 0; pr < 2; pr++) {
      u32x4 u;
#pragma unroll
      for (int sh = 0; sh < 2; sh++) {
        const int st = pr * 2 + sh;
        f32x4 s = (f32x4){0.f, 0.f, 0.f, 0.f};
        s = MFMA16(kf0s[st], q0, s);
        s = MFMA16(kf1s[st], q1, s);
        const int k0g = kbase + st * 16 + quad * 4;
        float pv[4];
#pragma unroll
        for (int r = 0; r < 4; r++) {
          float e = __builtin_amdgcn_exp2f(fmaf(s[r], SCALE_L2E, ROUND_B));
          if (masked && (k0g + r > qg)) e = 0.f;
          lx += e;
          pv[r] = e;
        }
        u[sh * 2] = pack2(pv[0], pv[1]);
        u[sh * 2 + 1] = pack2(pv[2], pv[3]);
      }
      Bp[pr] = __builtin_bit_cast(bf16x8, u);
    }
  };
  auto load_vfs = [&](const bf16_t* Vt, bf16x8* A8s) {
#pragma unroll
    for (int pr = 0; pr < 2; pr++) {
#pragma unroll
      for (int ct = 0; ct < 4; ct++) {
        const int dd = ct * 16 + ln;
        const int bc = (quad >> 1) + 2 * ct + (ln >> 3);
        const int cA = (4 * pr + bc) & 7;
        const int cB = (4 * pr + 2 + bc) & 7;
        bf16x4 v0 = *(const bf16x4*)&Vt[dd * VP + cA * 8 + (quad & 1) * 4];
        bf16x4 v1 = *(const bf16x4*)&Vt[dd * VP + cB * 8 + (quad & 1) * 4];
        A8s[pr * 4 + ct] = __builtin_shufflevector(v0, v1, 0, 1, 2, 3, 4, 5, 6, 7);
      }
    }
  };

  auto body = [&](int kt, bool hasA, bool maskA, bool maskB) {
    if (kt + 1 < ntiles) {
      stage_to((kt + 1) & 1);
      if (kt + 2 < ntiles) prefetch();
    }
    const bf16_t* Ks = &KsB[(kt & 1) * BUF];
    const bf16_t* Vt = &VtB[(kt & 1) * BUF];
    bf16x8 kf0s[4], kf1s[4];
    load_kfs(Ks, kf0s, kf1s);
    bf16x8 BpA[2], BpB[2];
    if (hasA) qk_block(kf0s, kf1s, qfA0, qfA1, lAx, BpA, maskA, kt * 64, qgA);
    qk_block(kf0s, kf1s, qfB0, qfB1, lBx, BpB, maskB, kt * 64, qgB);
    bf16x8 A8s[8];
    load_vfs(Vt, A8s);
#pragma unroll
    for (int pr = 0; pr < 2; pr++) {
#pragma unroll
      for (int ct = 0; ct < 4; ct++) {
        if (hasA) oA[ct] = MFMA16(A8s[pr * 4 + ct], BpA[pr], oA[ct]);
        oB[ct] = MFMA16(A8s[pr * 4 + ct], BpB[pr], oB[ct]);
      }
    }
    if (kt + 1 < ntiles) __syncthreads();
  };

  // prologue: tile 0 into buf0, prefetch tile 1, sync
  stage_to(0);
  if (ntiles > 1) prefetch();
  __syncthreads();

  // peeled phases: [0,p) AB | p A-diag | (p,31-p) B-only | 31-p B-diag
  for (int kt = 0; kt < p; kt++) body(kt, true, false, false);
  body(p, true, true, false);
  for (int kt = p + 1; kt < 31 - p; kt++) body(kt, false, false, false);
  body(31 - p, false, false, true);

  // l: sum partials across the 4 quads (k-direction), then normalize+store
  lAx += __shfl_xor(lAx, 16);
  lAx += __shfl_xor(lAx, 32);
  lBx += __shfl_xor(lBx, 16);
  lBx += __shfl_xor(lBx, 32);
  const float invA = __builtin_amdgcn_rcpf(lAx);
  const float invB = __builtin_amdgcn_rcpf(lBx);
  const int ocol = h * 64 + quad * 4;
#pragma unroll
  for (int ct = 0; ct < 4; ct++) {
    bf16x4 wa, wb;
#pragma unroll
    for (int r = 0; r < 4; r++) {
      wa[r] = (bf16_t)(oA[ct][r] * invA);
      wb[r] = (bf16_t)(oB[ct][r] * invB);
    }
    *(bf16x4*)&out[(size_t)(b * 2048 + qgA) * 1024 + ocol + ct * 16] = wa;
    *(bf16x4*)&out[(size_t)(b * 2048 + qgB) * 1024 + ocol + ct * 16] = wb;
  }
}

extern "C" void kernel_launch(void* const* d_in, const int* in_sizes, int n_in,
                              void* d_out, int out_size, void* d_ws, size_t ws_size,
                              hipStream_t stream) {
  const float* x     = (const float*)d_in[0];  // [2,2048,1024]
  const float* w_qkv = (const float*)d_in[1];  // [3072,1024]
  const float* b_qkv = (const float*)d_in[2];  // [3072]
  const float* w_o   = (const float*)d_in[3];  // [1024,1024]
  const float* b_o   = (const float*)d_in[4];  // [1024]
  float* out = (float*)d_out;                  // [2,2048,1024]

  // workspace (bf16): qkv | xbf/attn (aliased) | wqkv_bf | wo_bf  = 42 MB
  bf16_t* qkv   = (bf16_t*)d_ws;
  bf16_t* xbf   = qkv + (size_t)4096 * 3072;
  bf16_t* wqkvb = xbf + (size_t)4096 * 1024;
  bf16_t* wob   = wqkvb + (size_t)3072 * 1024;
  bf16_t* attn  = xbf;  // x dead after GEMM1

  const int na = 4096 * 1024, nb = 3072 * 1024, nc = 1024 * 1024;
  convert3_f32_bf16<<<dim3((na + nb + nc) / (256 * 8)), 256, 0, stream>>>(
      x, na, w_qkv, nb, w_o, nc, xbf, wqkvb, wob);

  // 1) qkv = x @ w_qkv^T + b_qkv   (768 blocks, 3/CU, BK=64)
  gemm_bt_bias<bf16_t, 128><<<dim3(3072 / 128, 4096 / 128), 256, 0, stream>>>(
      xbf, wqkvb, b_qkv, qkv, 4096, 3072, 1024);
  // 2) causal attention, paired q-tiles (p, 31-p): EXACTLY 512 blocks
  attn_kernel<<<dim3(512), 256, 0, stream>>>(qkv, attn);
  // 3) out = attn @ w_o^T + b_o    (128x64 tiles, 512 blocks, 2/CU, BK=64)
  gemm_bt_bias<float, 64><<<dim3(1024 / 64, 4096 / 128), 256, 0, stream>>>(
      attn, wob, b_o, out, 4096, 1024, 1024);
}